// Round 1
// baseline (26212.616 us; speedup 1.0000x reference)
//
#include <hip/hip_runtime.h>
#include <cmath>

#define NB 128
#define NT 256
#define DEMB 256
#define HH 512
#define NCLS 5
#define PADTOK 29999

// ---------------- step kernel ----------------
// Computes, for one timestep of one or two directions (blockIdx.z):
//   g = x_t @ wih^T + h_in @ whh^T + bih + bhh        (4H outputs)
//   c = sig(f)*c + sig(i)*tanh(g);  h = sig(o)*tanh(c)
// Tile: 16 batches x 16 hidden units; thread owns 2 batches x 4 gates.

struct StepP {
  const float* x; int x_rstride;       // input rows [b, K]
  const float* wih; const float* whh;  // [4H, KIN], [4H, H]
  const float* bih; const float* bhh;  // [4H]
  const float* h_in; float* h_out;     // [B, H] ping-pong
  float* c;                            // [B, H] in-place (one owner per element)
  float* hseq; int hseq_rstride;       // optional sequence write (already offset to t, dir)
};

__device__ __forceinline__ void gemm_seg(
    const float* __restrict__ src, int rs,
    const float* __restrict__ W, int ld, int K,
    int b0, int u0, int tid, int bl, int ul,
    float (&acc)[2][4], float (*xt)[36], float (*wt)[36]) {
  for (int k0 = 0; k0 < K; k0 += 32) {
    // stage x tile: 16 rows x 32 cols, 4 floats/thread
    {
      int row = tid >> 3;
      int col = (tid & 7) << 2;
      *(float4*)&xt[row][col] =
          *(const float4*)(src + (size_t)(b0 + row) * rs + k0 + col);
    }
    // stage w tile: 64 rows (4 gates x 16 u) x 32 cols, 4x float4/thread
#pragma unroll
    for (int i = 0; i < 4; ++i) {
      int f4 = (i << 7) + tid;
      int row = f4 >> 3;        // 0..63
      int c4 = (f4 & 7) << 2;   // 0..28
      int gate = row >> 4, ur = row & 15;
      *(float4*)&wt[row][c4] =
          *(const float4*)(W + (size_t)(gate * HH + u0 + ur) * ld + k0 + c4);
    }
    __syncthreads();
#pragma unroll
    for (int kk = 0; kk < 32; kk += 4) {
      float4 x0 = *(const float4*)&xt[bl][kk];
      float4 x1 = *(const float4*)&xt[bl + 8][kk];
#pragma unroll
      for (int g = 0; g < 4; ++g) {
        float4 w = *(const float4*)&wt[(g << 4) + ul][kk];
        acc[0][g] = fmaf(x0.x, w.x, fmaf(x0.y, w.y, fmaf(x0.z, w.z, fmaf(x0.w, w.w, acc[0][g]))));
        acc[1][g] = fmaf(x1.x, w.x, fmaf(x1.y, w.y, fmaf(x1.z, w.z, fmaf(x1.w, w.w, acc[1][g]))));
      }
    }
    __syncthreads();
  }
}

template<int KIN>
__global__ __launch_bounds__(128)
void lstm_step_kernel(StepP P0, StepP P1) {
  const StepP P = (blockIdx.z == 0) ? P0 : P1;
  __shared__ float xt[16][36];
  __shared__ float wt[64][36];
  // XCD-friendly swizzle: XCD (= lin%8 heuristic) gets 4 contiguous u-tiles so
  // its weight slice (~0.8-1.6 MB) stays L2-resident across all 256+ steps.
  int lin = (int)blockIdx.x + ((int)blockIdx.y << 3);          // grid (8,32)
  int b0 = ((lin >> 5) & 7) << 4;                               // 8 batch tiles
  int u0 = ((((lin & 7) << 2) | ((lin >> 3) & 3))) << 4;        // 32 u tiles
  int tid = threadIdx.x;
  int ul = tid & 15, bl = tid >> 4;

  float acc[2][4] = {{0.f,0.f,0.f,0.f},{0.f,0.f,0.f,0.f}};
  gemm_seg(P.x,    P.x_rstride, P.wih, KIN, KIN, b0, u0, tid, bl, ul, acc, xt, wt);
  gemm_seg(P.h_in, HH,          P.whh, HH,  HH,  b0, u0, tid, bl, ul, acc, xt, wt);

  int u = u0 + ul;
  float bi = P.bih[u]          + P.bhh[u];
  float bf = P.bih[HH + u]     + P.bhh[HH + u];
  float bg = P.bih[2 * HH + u] + P.bhh[2 * HH + u];
  float bo = P.bih[3 * HH + u] + P.bhh[3 * HH + u];
#pragma unroll
  for (int j = 0; j < 2; ++j) {
    int b = b0 + bl + (j << 3);
    size_t idx = (size_t)b * HH + u;
    float gi = acc[j][0] + bi, gf = acc[j][1] + bf;
    float gg = acc[j][2] + bg, go = acc[j][3] + bo;
    float si = 1.f / (1.f + expf(-gi));
    float sf = 1.f / (1.f + expf(-gf));
    float so = 1.f / (1.f + expf(-go));
    float cn = sf * P.c[idx] + si * tanhf(gg);
    float hn = so * tanhf(cn);
    P.c[idx] = cn;
    P.h_out[idx] = hn;
    if (P.hseq) P.hseq[(size_t)b * P.hseq_rstride + u] = hn;
  }
}

// ---------------- embedding ----------------
__global__ __launch_bounds__(64)
void embed_kernel(const int* __restrict__ xw, const float* __restrict__ emb,
                  float* __restrict__ xe) {
  int bt = blockIdx.x;            // b*T + t
  int tok = xw[bt];
  int c = threadIdx.x << 2;       // 64 lanes x 4 floats = 256
  float4 v = make_float4(0.f, 0.f, 0.f, 0.f);
  if (tok != PADTOK) v = *(const float4*)(emb + (size_t)tok * DEMB + c);
  *(float4*)(xe + (size_t)bt * DEMB + c) = v;
}

// ---------------- classifier ----------------
__global__ __launch_bounds__(128)
void cls_kernel(const float* __restrict__ hf, const float* __restrict__ hr,
                const float* __restrict__ wout, const float* __restrict__ bout,
                float* __restrict__ out) {
  int b = blockIdx.x;
  int tid = threadIdx.x;
  float p[NCLS] = {0.f, 0.f, 0.f, 0.f, 0.f};
  for (int j = tid; j < HH; j += 128) {
    float v = hf[(size_t)b * HH + j];
#pragma unroll
    for (int n = 0; n < NCLS; ++n) p[n] += v * wout[n * (2 * HH) + j];
  }
  for (int j = tid; j < HH; j += 128) {
    float v = hr[(size_t)b * HH + j];
#pragma unroll
    for (int n = 0; n < NCLS; ++n) p[n] += v * wout[n * (2 * HH) + HH + j];
  }
  __shared__ float red[NCLS][128];
  for (int n = 0; n < NCLS; ++n) red[n][tid] = p[n];
  __syncthreads();
  for (int s = 64; s > 0; s >>= 1) {
    if (tid < s)
      for (int n = 0; n < NCLS; ++n) red[n][tid] += red[n][tid + s];
    __syncthreads();
  }
  if (tid == 0)
    for (int n = 0; n < NCLS; ++n) out[b * NCLS + n] = red[n][0] + bout[n];
}

// ---------------- launch ----------------
extern "C" void kernel_launch(void* const* d_in, const int* in_sizes, int n_in,
                              void* d_out, int out_size, void* d_ws, size_t ws_size,
                              hipStream_t stream) {
  const int*   xw    = (const int*)  d_in[0];
  const float* emb   = (const float*)d_in[1];
  const float* wih0f = (const float*)d_in[2];
  const float* whh0f = (const float*)d_in[3];
  const float* bih0f = (const float*)d_in[4];
  const float* bhh0f = (const float*)d_in[5];
  const float* wih0r = (const float*)d_in[6];
  const float* whh0r = (const float*)d_in[7];
  const float* bih0r = (const float*)d_in[8];
  const float* bhh0r = (const float*)d_in[9];
  const float* wih1f = (const float*)d_in[10];
  const float* whh1f = (const float*)d_in[11];
  const float* bih1f = (const float*)d_in[12];
  const float* bhh1f = (const float*)d_in[13];
  const float* wih1r = (const float*)d_in[14];
  const float* whh1r = (const float*)d_in[15];
  const float* bih1r = (const float*)d_in[16];
  const float* bhh1r = (const float*)d_in[17];
  const float* wout  = (const float*)d_in[18];
  const float* bout  = (const float*)d_in[19];
  float* out = (float*)d_out;

  float* ws = (float*)d_ws;
  const size_t XE  = (size_t)NB * NT * DEMB;      // 8,388,608 floats
  const size_t H0S = (size_t)NB * NT * 2 * HH;    // 33,554,432 floats
  const size_t BH  = (size_t)NB * HH;             // 65,536 floats
  float* xe = ws;
  float* h0 = xe + XE;                            // [B, T, f(512)|r(512)]
  float* st = h0 + H0S;                           // 12 x BH state buffers
  float* l0f_h[2] = { st + 0 * BH, st + 1 * BH };  float* l0f_c = st + 2 * BH;
  float* l0r_h[2] = { st + 3 * BH, st + 4 * BH };  float* l0r_c = st + 5 * BH;
  float* l1f_h[2] = { st + 6 * BH, st + 7 * BH };  float* l1f_c = st + 8 * BH;
  float* l1r_h[2] = { st + 9 * BH, st + 10 * BH }; float* l1r_c = st + 11 * BH;

  // zero all scan states (h ping-pong inputs at s=0 and all c)
  hipMemsetAsync(st, 0, 12 * BH * sizeof(float), stream);

  // embedding (PAD row -> 0)
  embed_kernel<<<dim3(NB * NT), dim3(64), 0, stream>>>(xw, emb, xe);

  dim3 blk(128);
  const int hs_rs = NT * 2 * HH;

  // ---- layer 0: both directions per launch (z=2) ----
  {
    dim3 g0(8, 32, 2);
    for (int s = 0; s < NT; ++s) {
      int tf = s, tr = NT - 1 - s;
      StepP pf, pr;
      pf.x = xe + (size_t)tf * DEMB; pf.x_rstride = NT * DEMB;
      pf.wih = wih0f; pf.whh = whh0f; pf.bih = bih0f; pf.bhh = bhh0f;
      pf.h_in = l0f_h[s & 1]; pf.h_out = l0f_h[(s + 1) & 1]; pf.c = l0f_c;
      pf.hseq = h0 + (size_t)tf * (2 * HH); pf.hseq_rstride = hs_rs;
      pr.x = xe + (size_t)tr * DEMB; pr.x_rstride = NT * DEMB;
      pr.wih = wih0r; pr.whh = whh0r; pr.bih = bih0r; pr.bhh = bhh0r;
      pr.h_in = l0r_h[s & 1]; pr.h_out = l0r_h[(s + 1) & 1]; pr.c = l0r_c;
      pr.hseq = h0 + (size_t)tr * (2 * HH) + HH; pr.hseq_rstride = hs_rs;
      lstm_step_kernel<DEMB><<<g0, blk, 0, stream>>>(pf, pr);
    }
  }

  // ---- layer 1 forward: full scan (z=1) ----
  {
    dim3 g1(8, 32, 1);
    for (int s = 0; s < NT; ++s) {
      StepP p;
      p.x = h0 + (size_t)s * (2 * HH); p.x_rstride = hs_rs;
      p.wih = wih1f; p.whh = whh1f; p.bih = bih1f; p.bhh = bhh1f;
      p.h_in = l1f_h[s & 1]; p.h_out = l1f_h[(s + 1) & 1]; p.c = l1f_c;
      p.hseq = nullptr; p.hseq_rstride = 0;
      lstm_step_kernel<2 * HH><<<g1, blk, 0, stream>>>(p, p);
    }
  }

  // ---- layer 1 reverse: only hs[T-1] is consumed = ONE step from zero state ----
  {
    dim3 g1(8, 32, 1);
    StepP p;
    p.x = h0 + (size_t)(NT - 1) * (2 * HH); p.x_rstride = hs_rs;
    p.wih = wih1r; p.whh = whh1r; p.bih = bih1r; p.bhh = bhh1r;
    p.h_in = l1r_h[0]; p.h_out = l1r_h[1]; p.c = l1r_c;   // zeroed inputs
    p.hseq = nullptr; p.hseq_rstride = 0;
    lstm_step_kernel<2 * HH><<<g1, blk, 0, stream>>>(p, p);
  }

  // ---- classifier: concat(l1f final = ping[0] after 256 steps, l1r step-1 out) ----
  cls_kernel<<<dim3(NB), dim3(128), 0, stream>>>(l1f_h[0], l1r_h[1], wout, bout, out);
}

// Round 3
// 5220.219 us; speedup vs baseline: 5.0214x; 5.0214x over previous
//
#include <hip/hip_runtime.h>
#include <cmath>

#define NB 128
#define NT 256
#define DEMB 256
#define HH 512
#define NCLS 5
#define PADTOK 29999
#define TC 32          // timestep chunk for xg materialization

typedef __attribute__((ext_vector_type(8))) short bfrag;   // 8 bf16 (4 VGPRs)
typedef __attribute__((ext_vector_type(4))) float faccv;   // 4 fp32 acc

__device__ __forceinline__ unsigned short f2bf(float f) {
  union { float f; unsigned u; } v; v.f = f;
  unsigned r = v.u + 0x7fff + ((v.u >> 16) & 1);   // RNE
  return (unsigned short)(r >> 16);
}
__device__ __forceinline__ float bf2f(unsigned short h) {
  union { unsigned u; float f; } v; v.u = (unsigned)h << 16;
  return v.f;
}
__device__ __forceinline__ float sigf(float x) { return 1.f / (1.f + expf(-x)); }

// ---------------- fp32 -> bf16 convert ----------------
__global__ __launch_bounds__(256)
void cvt_bf16(const float* __restrict__ src, unsigned short* __restrict__ dst, int n) {
  int i = (blockIdx.x * 256 + threadIdx.x) * 4;
  if (i < n) {
    float4 v = *(const float4*)(src + i);
    dst[i + 0] = f2bf(v.x); dst[i + 1] = f2bf(v.y);
    dst[i + 2] = f2bf(v.z); dst[i + 3] = f2bf(v.w);
  }
}

// ---------------- embedding -> bf16, t-major [T,B,256] ----------------
__global__ __launch_bounds__(64)
void embed_kernel(const int* __restrict__ xw, const float* __restrict__ emb,
                  unsigned short* __restrict__ xe) {
  int bt = blockIdx.x;            // b*T + t  (matches x layout [B,T])
  int b = bt >> 8, t = bt & 255;
  int tok = xw[bt];
  int c = threadIdx.x << 2;
  float4 v = make_float4(0.f, 0.f, 0.f, 0.f);
  if (tok != PADTOK) v = *(const float4*)(emb + (size_t)tok * DEMB + c);
  ushort4 o;
  o.x = f2bf(v.x); o.y = f2bf(v.y); o.z = f2bf(v.z); o.w = f2bf(v.w);
  *(ushort4*)(xe + ((size_t)t * NB + b) * DEMB + c) = o;
}

// ---------------- MFMA GEMM: C[M,2048] = A[M,K] @ W[2048,K]^T + b1 + b2 ----
// A rows contiguous at stride a_rstride. 128x128 tile, 4 waves, BK=32.
__global__ __launch_bounds__(256)
void gemm_xg(const unsigned short* __restrict__ A, long a_rstride,
             const unsigned short* __restrict__ W, int K,
             const float* __restrict__ b1, const float* __restrict__ b2,
             unsigned short* __restrict__ C) {
  __shared__ unsigned short At[128 * 32];
  __shared__ unsigned short Bt[128 * 32];
  int tid = threadIdx.x;
  int w = tid >> 6, l = tid & 63;
  int q = l >> 4, r16 = l & 15;
  long m0 = (long)blockIdx.x * 128;
  int n0 = blockIdx.y * 128;
  int wm = (w & 1) * 64, wn = (w >> 1) * 64;
  faccv acc[4][4] = {};

  int srow = tid >> 1;
  const unsigned short* Ag = A + (m0 + srow) * a_rstride + (tid & 1) * 8;
  const unsigned short* Wg = W + (long)(n0 + srow) * K + (tid & 1) * 8;

  for (int k0 = 0; k0 < K; k0 += 32) {
    __syncthreads();
    *(float4*)&At[srow * 32 + (tid & 1) * 8]      = *(const float4*)(Ag + k0);
    *(float4*)&At[srow * 32 + (tid & 1) * 8 + 16] = *(const float4*)(Ag + k0 + 16);
    *(float4*)&Bt[srow * 32 + (tid & 1) * 8]      = *(const float4*)(Wg + k0);
    *(float4*)&Bt[srow * 32 + (tid & 1) * 8 + 16] = *(const float4*)(Wg + k0 + 16);
    __syncthreads();
    bfrag af[4], bf[4];
#pragma unroll
    for (int i = 0; i < 4; ++i) {
      af[i] = *(const bfrag*)&At[(wm + i * 16 + r16) * 32 + q * 8];
      bf[i] = *(const bfrag*)&Bt[(wn + i * 16 + r16) * 32 + q * 8];
    }
#pragma unroll
    for (int mf = 0; mf < 4; ++mf)
#pragma unroll
      for (int nf = 0; nf < 4; ++nf)
        acc[mf][nf] = __builtin_amdgcn_mfma_f32_16x16x32_bf16(af[mf], bf[nf], acc[mf][nf], 0, 0, 0);
  }
#pragma unroll
  for (int nf = 0; nf < 4; ++nf) {
    int col = n0 + wn + nf * 16 + r16;
    float bs = b1[col] + b2[col];
#pragma unroll
    for (int mf = 0; mf < 4; ++mf) {
#pragma unroll
      for (int r = 0; r < 4; ++r) {
        long row = m0 + wm + mf * 16 + q * 4 + r;
        C[row * 2048 + col] = f2bf(acc[mf][nf][r] + bs);
      }
    }
  }
}

// ---------------- recurrent scan step (MFMA) ----------------
// Block: 16 gate-cols (units u0..u0+3 x 4 gates), NBT batches.
// g[b,m] = xg[tt,b,m] + sum_k whh[m,k] h_in[b,k]; then LSTM pointwise.
struct ScanP {
  const unsigned short* xg_t;   // chunk + tt*NB*2048; batch stride 2048
  const unsigned short* whh;    // [2048,512] bf16
  const unsigned short* h_in;   // [128,512] bf16
  unsigned short* h_out;        // [128,512] bf16
  float* c;                     // [128,512] fp32
  unsigned short* hseq_t;       // h0 + t*NB*1024 + dir*512 (or null); batch stride 1024
  int b0;
};

template<int NBT>
__global__ __launch_bounds__(256)
void lstm_scan_step(ScanP P0, ScanP P1) {
  const ScanP P = blockIdx.y ? P1 : P0;
  const int u0 = blockIdx.x * 4;
  __shared__ unsigned short Wt[16 * 520];
  __shared__ unsigned short Ht[NBT * 72];
  int tid = threadIdx.x;
  int w = tid >> 6, l = tid & 63, q = l >> 4, n16 = l & 15;
  constexpr int NF = NBT / 64;

  // stage weight slice once: 16 rows (m = unit*4+gate) x 512
#pragma unroll
  for (int i = 0; i < 4; ++i) {
    int f4 = tid + i * 256;
    int row = f4 >> 6, c8 = (f4 & 63) * 8;
    int unit = row >> 2, gate = row & 3;
    *(float4*)&Wt[row * 520 + c8] =
        *(const float4*)(P.whh + (size_t)(gate * HH + u0 + unit) * HH + c8);
  }

  // init acc from xg (biases already folded)
  faccv acc[NF];
#pragma unroll
  for (int nf = 0; nf < NF; ++nf) {
    int b = P.b0 + (w * NF + nf) * 16 + n16;
    const unsigned short* xr = P.xg_t + (size_t)b * 2048;
    faccv a;
    a[0] = bf2f(xr[0 * HH + u0 + q]);
    a[1] = bf2f(xr[1 * HH + u0 + q]);
    a[2] = bf2f(xr[2 * HH + u0 + q]);
    a[3] = bf2f(xr[3 * HH + u0 + q]);
    acc[nf] = a;
  }
  __syncthreads();   // Wt ready

#pragma unroll
  for (int ch = 0; ch < 8; ++ch) {
    if (ch) __syncthreads();
#pragma unroll
    for (int i = 0; i < NBT / 32; ++i) {
      int s4 = tid + i * 256;
      int row = s4 >> 3, seg = s4 & 7;
      *(float4*)&Ht[row * 72 + seg * 8] =
          *(const float4*)(P.h_in + (size_t)(P.b0 + row) * HH + ch * 64 + seg * 8);
    }
    __syncthreads();
    bfrag af0 = *(const bfrag*)&Wt[n16 * 520 + ch * 64 + q * 8];
    bfrag af1 = *(const bfrag*)&Wt[n16 * 520 + ch * 64 + 32 + q * 8];
#pragma unroll
    for (int nf = 0; nf < NF; ++nf) {
      int rowb = (w * NF + nf) * 16 + n16;
      bfrag bf0 = *(const bfrag*)&Ht[rowb * 72 + q * 8];
      bfrag bf1 = *(const bfrag*)&Ht[rowb * 72 + 32 + q * 8];
      acc[nf] = __builtin_amdgcn_mfma_f32_16x16x32_bf16(af0, bf0, acc[nf], 0, 0, 0);
      acc[nf] = __builtin_amdgcn_mfma_f32_16x16x32_bf16(af1, bf1, acc[nf], 0, 0, 0);
    }
  }

  // pointwise: lane holds all 4 gates (reg) of unit u0+q for batch n16
#pragma unroll
  for (int nf = 0; nf < NF; ++nf) {
    int b = P.b0 + (w * NF + nf) * 16 + n16;
    int u = u0 + q;
    size_t ci = (size_t)b * HH + u;
    float cn = sigf(acc[nf][1]) * P.c[ci] + sigf(acc[nf][0]) * tanhf(acc[nf][2]);
    float hn = sigf(acc[nf][3]) * tanhf(cn);
    P.c[ci] = cn;
    P.h_out[ci] = f2bf(hn);
    if (P.hseq_t) P.hseq_t[(size_t)b * 1024 + u] = f2bf(hn);
  }
}

// ---------------- layer-1 reverse single step (c_prev = h_prev = 0) ------
__global__ __launch_bounds__(512)
void pw_l1r(const unsigned short* __restrict__ xg, unsigned short* __restrict__ h1r) {
  int b = blockIdx.x, u = threadIdx.x;
  float gi = bf2f(xg[(size_t)b * 2048 + u]);
  float gg = bf2f(xg[(size_t)b * 2048 + 2 * HH + u]);
  float go = bf2f(xg[(size_t)b * 2048 + 3 * HH + u]);
  float cn = sigf(gi) * tanhf(gg);
  h1r[(size_t)b * HH + u] = f2bf(sigf(go) * tanhf(cn));
}

// ---------------- classifier ----------------
__global__ __launch_bounds__(128)
void cls_kernel(const unsigned short* __restrict__ hf, const unsigned short* __restrict__ hr,
                const float* __restrict__ wout, const float* __restrict__ bout,
                float* __restrict__ out) {
  int b = blockIdx.x;
  int tid = threadIdx.x;
  float p[NCLS] = {0.f, 0.f, 0.f, 0.f, 0.f};
  for (int j = tid; j < HH; j += 128) {
    float v = bf2f(hf[(size_t)b * HH + j]);
#pragma unroll
    for (int n = 0; n < NCLS; ++n) p[n] += v * wout[n * (2 * HH) + j];
  }
  for (int j = tid; j < HH; j += 128) {
    float v = bf2f(hr[(size_t)b * HH + j]);
#pragma unroll
    for (int n = 0; n < NCLS; ++n) p[n] += v * wout[n * (2 * HH) + HH + j];
  }
  __shared__ float red[NCLS][128];
  for (int n = 0; n < NCLS; ++n) red[n][tid] = p[n];
  __syncthreads();
  for (int s = 64; s > 0; s >>= 1) {
    if (tid < s)
      for (int n = 0; n < NCLS; ++n) red[n][tid] += red[n][tid + s];
    __syncthreads();
  }
  if (tid == 0)
    for (int n = 0; n < NCLS; ++n) out[b * NCLS + n] = red[n][0] + bout[n];
}

// ---------------- host ----------------
extern "C" void kernel_launch(void* const* d_in, const int* in_sizes, int n_in,
                              void* d_out, int out_size, void* d_ws, size_t ws_size,
                              hipStream_t stream) {
  const int*   xw    = (const int*)  d_in[0];
  const float* emb   = (const float*)d_in[1];
  const float* wih0f = (const float*)d_in[2];
  const float* whh0f = (const float*)d_in[3];
  const float* bih0f = (const float*)d_in[4];
  const float* bhh0f = (const float*)d_in[5];
  const float* wih0r = (const float*)d_in[6];
  const float* whh0r = (const float*)d_in[7];
  const float* bih0r = (const float*)d_in[8];
  const float* bhh0r = (const float*)d_in[9];
  const float* wih1f = (const float*)d_in[10];
  const float* whh1f = (const float*)d_in[11];
  const float* bih1f = (const float*)d_in[12];
  const float* bhh1f = (const float*)d_in[13];
  const float* wih1r = (const float*)d_in[14];
  const float* whh1r = (const float*)d_in[15];
  const float* bih1r = (const float*)d_in[16];
  const float* bhh1r = (const float*)d_in[17];
  const float* wout  = (const float*)d_in[18];
  const float* bout  = (const float*)d_in[19];
  float* out = (float*)d_out;
  (void)whh1r; (void)ws_size;

  // ---- workspace bump allocator (~130 MB total; round-1 proved >=163 MB ok) ----
  char* base = (char*)d_ws;
  size_t off = 0;
  auto alloc = [&](size_t bytes) {
    char* p = base + off;
    off += (bytes + 255) & ~(size_t)255;
    return p;
  };
  unsigned short* xe  = (unsigned short*)alloc((size_t)NT * NB * DEMB * 2);  // 16 MB t-major
  unsigned short* h0  = (unsigned short*)alloc((size_t)NT * NB * 1024 * 2);  // 64 MB t-major
  unsigned short* xgf = (unsigned short*)alloc((size_t)TC * NB * 2048 * 2);  // 16 MB chunk
  unsigned short* xgr = (unsigned short*)alloc((size_t)TC * NB * 2048 * 2);  // 16 MB chunk
  unsigned short* xg1r = (unsigned short*)alloc((size_t)NB * 2048 * 2);      // 0.5 MB
  unsigned short* wb_wih0f = (unsigned short*)alloc(2048 * 256 * 2);
  unsigned short* wb_whh0f = (unsigned short*)alloc(2048 * 512 * 2);
  unsigned short* wb_wih0r = (unsigned short*)alloc(2048 * 256 * 2);
  unsigned short* wb_whh0r = (unsigned short*)alloc(2048 * 512 * 2);
  unsigned short* wb_wih1f = (unsigned short*)alloc(2048 * 1024 * 2);
  unsigned short* wb_wih1r = (unsigned short*)alloc(2048 * 1024 * 2);
  unsigned short* wb_whh1f = (unsigned short*)alloc(2048 * 512 * 2);
  char* stbase = alloc(7 * (size_t)NB * HH * 2 + 3 * (size_t)NB * HH * 4);
  unsigned short* hf_p[2] = {(unsigned short*)stbase,
                             (unsigned short*)(stbase + (size_t)NB * HH * 2)};
  unsigned short* hr_p[2] = {(unsigned short*)(stbase + 2 * (size_t)NB * HH * 2),
                             (unsigned short*)(stbase + 3 * (size_t)NB * HH * 2)};
  unsigned short* h1_p[2] = {(unsigned short*)(stbase + 4 * (size_t)NB * HH * 2),
                             (unsigned short*)(stbase + 5 * (size_t)NB * HH * 2)};
  unsigned short* h1r = (unsigned short*)(stbase + 6 * (size_t)NB * HH * 2);
  float* cf = (float*)(stbase + 7 * (size_t)NB * HH * 2);
  float* cr = cf + (size_t)NB * HH;
  float* c1 = cr + (size_t)NB * HH;

  hipMemsetAsync(stbase, 0, 7 * (size_t)NB * HH * 2 + 3 * (size_t)NB * HH * 4, stream);

  // ---- weights -> bf16 ----
  auto cvt = [&](const float* s, unsigned short* d, int n) {
    cvt_bf16<<<dim3((n / 4 + 255) / 256), dim3(256), 0, stream>>>(s, d, n);
  };
  cvt(wih0f, wb_wih0f, 2048 * 256);
  cvt(whh0f, wb_whh0f, 2048 * 512);
  cvt(wih0r, wb_wih0r, 2048 * 256);
  cvt(whh0r, wb_whh0r, 2048 * 512);
  cvt(wih1f, wb_wih1f, 2048 * 1024);
  cvt(wih1r, wb_wih1r, 2048 * 1024);
  cvt(whh1f, wb_whh1f, 2048 * 512);

  // ---- embedding (t-major) ----
  embed_kernel<<<dim3(NB * NT), dim3(64), 0, stream>>>(xw, emb, xe);

  const int NG = NT / TC;                 // 8 chunk groups
  const size_t XROW = (size_t)NB * DEMB;  // xe timestep stride
  const size_t GROW = (size_t)NB * 2048;  // xg timestep stride
  const size_t HROW = (size_t)NB * 1024;  // h0 timestep stride

  // ---- layer 0: chunked input GEMMs + fused 2-dir scan ----
  for (int g = 0; g < NG; ++g) {
    gemm_xg<<<dim3(TC * NB / 128, 16), dim3(256), 0, stream>>>(
        xe + (size_t)g * TC * XROW, DEMB, wb_wih0f, DEMB, bih0f, bhh0f, xgf);
    gemm_xg<<<dim3(TC * NB / 128, 16), dim3(256), 0, stream>>>(
        xe + (size_t)(NG - 1 - g) * TC * XROW, DEMB, wb_wih0r, DEMB, bih0r, bhh0r, xgr);
    for (int j = 0; j < TC; ++j) {
      int s = g * TC + j;
      int tf = s, tr = NT - 1 - s;
      ScanP pf, pr;
      pf.xg_t = xgf + (size_t)j * GROW;
      pf.whh = wb_whh0f;
      pf.h_in = hf_p[s & 1]; pf.h_out = hf_p[(s + 1) & 1]; pf.c = cf;
      pf.hseq_t = h0 + (size_t)tf * HROW;            // fwd -> cols 0..511
      pf.b0 = 0;
      pr.xg_t = xgr + (size_t)(TC - 1 - j) * GROW;
      pr.whh = wb_whh0r;
      pr.h_in = hr_p[s & 1]; pr.h_out = hr_p[(s + 1) & 1]; pr.c = cr;
      pr.hseq_t = h0 + (size_t)tr * HROW + HH;       // rev -> cols 512..1023
      pr.b0 = 0;
      lstm_scan_step<128><<<dim3(128, 2), dim3(256), 0, stream>>>(pf, pr);
    }
  }

  // ---- layer 1 reverse: one step from zero state ----
  gemm_xg<<<dim3(1, 16), dim3(256), 0, stream>>>(
      h0 + (size_t)(NT - 1) * HROW, 1024, wb_wih1r, 1024, bih1r, bhh1r, xg1r);
  pw_l1r<<<dim3(NB), dim3(512), 0, stream>>>(xg1r, h1r);

  // ---- layer 1 forward: chunked input GEMMs + scan ----
  for (int g = 0; g < NG; ++g) {
    gemm_xg<<<dim3(TC * NB / 128, 16), dim3(256), 0, stream>>>(
        h0 + (size_t)g * TC * HROW, 1024, wb_wih1f, 1024, bih1f, bhh1f, xgf);
    for (int j = 0; j < TC; ++j) {
      int s = g * TC + j;
      ScanP p0, p1;
      p0.xg_t = xgf + (size_t)j * GROW;
      p0.whh = wb_whh1f;
      p0.h_in = h1_p[s & 1]; p0.h_out = h1_p[(s + 1) & 1]; p0.c = c1;
      p0.hseq_t = nullptr;
      p0.b0 = 0;
      p1 = p0; p1.b0 = 64;
      lstm_scan_step<64><<<dim3(128, 2), dim3(256), 0, stream>>>(p0, p1);
    }
  }

  // ---- classifier ----
  cls_kernel<<<dim3(NB), dim3(128), 0, stream>>>(h1_p[0], h1r, wout, bout, out);
}